// Round 5
// baseline (4243.291 us; speedup 1.0000x reference)
//
#include <hip/hip_runtime.h>

#define CH    256
#define NTOK  2304
#define MATSZ (CH * NTOK)   // 589824 elements per (b, matrix)

typedef __bf16 bf16x8 __attribute__((ext_vector_type(8)));
typedef float  f4v    __attribute__((ext_vector_type(4)));
typedef unsigned int u32x4 __attribute__((ext_vector_type(4)));

__device__ __forceinline__ unsigned short f2bf(float f) {
    union { float f; unsigned int i; } c;
    c.f = f;
    unsigned int x = c.i;
    x += 0x7fffu + ((x >> 16) & 1u);   // round-to-nearest-even
    return (unsigned short)(x >> 16);
}

__device__ __forceinline__ bf16x8 cvt8(const float* p) {
    union { bf16x8 v; unsigned short s[8]; } u;
#pragma unroll
    for (int i = 0; i < 8; ++i) u.s[i] = f2bf(p[i]);
    return u.v;
}

// ---------------------------------------------------------------------------
// 64x64-tiled transpose + fp32->bf16: in (R x Ccols) row-major fp32 ->
// out (Ccols x R) bf16. blockIdx.y = s*8 + b (s: 0=left 1=right).
// Only used to build XT[pos][c] for the projection's B-operand.
// ---------------------------------------------------------------------------
__global__ __launch_bounds__(256) void tpose_k(
    const float* __restrict__ inL,
    const float* __restrict__ inR,
    unsigned short* __restrict__ out, int R, int Ccols)
{
    __shared__ unsigned short tile[64][72];
    int mat = blockIdx.y;
    const float* in = (mat >= 8 ? inR : inL) + (size_t)(mat & 7) * MATSZ;
    unsigned short* o = out + (size_t)mat * MATSZ;
    int tC = Ccols >> 6;
    int r0 = (blockIdx.x / tC) << 6;
    int c0 = (blockIdx.x % tC) << 6;
    int t = threadIdx.x;
    int col = t & 63, rs = t >> 6;
#pragma unroll
    for (int i = 0; i < 16; ++i) {
        int row = rs + i * 4;
        tile[row][col] = f2bf(in[(size_t)(r0 + row) * Ccols + c0 + col]);
    }
    __syncthreads();
#pragma unroll
    for (int i = 0; i < 16; ++i) {
        int crow = rs + i * 4;
        o[(size_t)(c0 + crow) * R + r0 + col] = tile[col][crow];
    }
}

// ---------------------------------------------------------------------------
// Projection: Y[o][pos] = BN(conv1x1(X)), bf16, (o, pos) layout.
// blockIdx.y = p*8 + b; p: 0=q(left) 1=q(right) 2=k(left) 3=k(right).
// ---------------------------------------------------------------------------
__global__ __launch_bounds__(256, 2) void proj_k(
    const unsigned short* __restrict__ XT,   // [2][8][2304][256] bf16
    const float* __restrict__ Wq_, const float* __restrict__ Wk_,
    const float* __restrict__ bq_, const float* __restrict__ bk_,
    const float* __restrict__ gq_, const float* __restrict__ gk_,
    const float* __restrict__ beq_, const float* __restrict__ bek_,
    const float* __restrict__ mq_, const float* __restrict__ mk_,
    const float* __restrict__ vq_, const float* __restrict__ vk_,
    unsigned short* __restrict__ Yout)       // [4][8][MATSZ] bf16
{
    __shared__ __align__(16) unsigned short Xs[64][264];
    int pb = blockIdx.y;
    int p = pb >> 3, b = pb & 7;
    int s = p & 1, br = p >> 1;
    const unsigned short* X = XT + (size_t)(s * 8 + b) * MATSZ;
    const float* W  = br ? Wk_ : Wq_;
    const float* bb = br ? bk_ : bq_;
    const float* gg = br ? gk_ : gq_;
    const float* be = br ? bek_ : beq_;
    const float* mm = br ? mk_ : mq_;
    const float* vv = br ? vk_ : vq_;
    unsigned short* Yo = Yout + (size_t)pb * MATSZ;

    int ot = blockIdx.x & 3, pt = blockIdx.x >> 2;
    int o0 = ot * 64, pos0 = pt * 64;
    int t = threadIdx.x;
    int w = t >> 6, lane = t & 63;
    int l15 = lane & 15, quad = lane >> 4;

    {   // stage XT tile: 64 pos-rows x 256 c
        int r = t >> 2, cq = (t & 3) << 6;
        const unsigned short* src = X + (size_t)(pos0 + r) * CH + cq;
        unsigned short* dst = &Xs[r][cq];
#pragma unroll
        for (int k = 0; k < 8; ++k)
            *(u32x4*)(dst + k * 8) = *(const u32x4*)(src + k * 8);
    }
    bf16x8 wf[8];
    {
        const float* wp = W + (size_t)(o0 + w * 16 + l15) * CH + quad * 8;
#pragma unroll
        for (int kc = 0; kc < 8; ++kc)
            wf[kc] = cvt8(wp + kc * 32);
    }
    __syncthreads();

    f4v zero4 = {0.f, 0.f, 0.f, 0.f};
    f4v acc[4] = {zero4, zero4, zero4, zero4};
#pragma unroll
    for (int kc = 0; kc < 8; ++kc) {
#pragma unroll
        for (int ct = 0; ct < 4; ++ct) {
            bf16x8 xb = *(const bf16x8*)(&Xs[ct * 16 + l15][kc * 32 + quad * 8]);
            acc[ct] = __builtin_amdgcn_mfma_f32_16x16x32_bf16(wf[kc], xb, acc[ct], 0, 0, 0);
        }
    }
#pragma unroll
    for (int r = 0; r < 4; ++r) {
        int o = o0 + w * 16 + quad * 4 + r;
        float scale = gg[o] * rsqrtf(vv[o] + 1e-5f);
        float shift = (bb[o] - mm[o]) * scale + be[o];
#pragma unroll
        for (int ct = 0; ct < 4; ++ct) {
            float val = acc[ct][r] * scale + shift;
            Yo[(size_t)o * NTOK + pos0 + ct * 16 + l15] = f2bf(val);
        }
    }
}

// ---------------------------------------------------------------------------
// Fused attention: QK^T by MFMA, PV by VALU FMAs (audited-simple baseline).
// V tile staged straight from the fp32 input (64-key tile of the raw
// (2304,256) view = 16384 contiguous floats). P kept fp32 in (q,key) layout.
// OUTPUT IS FP32 (reference output dtype).
// ---------------------------------------------------------------------------
__global__ __launch_bounds__(256, 1) void attn_k(
    const unsigned short* __restrict__ Y,    // [4][8][MATSZ] projections bf16
    const float* __restrict__ feaL, const float* __restrict__ feaR,
    float* __restrict__ out)                 // [2][8][MATSZ] fp32
{
    __shared__ __align__(16) unsigned short Ks[64 * 264]; // 33792 B
    __shared__ __align__(16) float Vs[64 * 260];          // 66560 B
    __shared__ __align__(16) float Psf[64 * 65];          // 16640 B
    __shared__ float Ls[64];

    int ab = blockIdx.y;
    int a = ab >> 3, b = ab & 7;
    int qt = blockIdx.x;
    const unsigned short* Qp = Y + (size_t)(a * 8 + b) * MATSZ;        // q(l)/q(r)
    const unsigned short* Kp = Y + (size_t)((3 - a) * 8 + b) * MATSZ;  // k(r)/k(l)
    const float* Vf = (a ? feaL : feaR) + (size_t)b * MATSZ;           // raw V
    float* Op = out + (size_t)ab * MATSZ;

    int t = threadIdx.x;
    int w = t >> 6, lane = t & 63;
    int l15 = lane & 15, quad = lane >> 4;
    int vq = t >> 2, vg = t & 3;   // VALU-PV mapping: q-row, channel quarter

    bf16x8 qf[8];
    {
        const unsigned short* qp = Qp + (size_t)(qt * 64 + w * 16 + l15) * CH + quad * 8;
#pragma unroll
        for (int kc = 0; kc < 8; ++kc) qf[kc] = *(const bf16x8*)(qp + kc * 32);
    }
    f4v zero4 = {0.f, 0.f, 0.f, 0.f};
    float l_acc[4] = {0.f, 0.f, 0.f, 0.f};
    float oacc[64];
#pragma unroll
    for (int i = 0; i < 64; ++i) oacc[i] = 0.f;

    for (int kt = 0; kt < 36; ++kt) {
        __syncthreads();
        {   // stage K tile: 64 key-rows x 256 c (bf16), stride 264
            int r = t >> 2, cq = (t & 3) << 6;
            const unsigned short* src = Kp + (size_t)(kt * 64 + r) * CH + cq;
            unsigned short* dst = Ks + r * 264 + cq;
#pragma unroll
            for (int k = 0; k < 8; ++k)
                *(u32x4*)(dst + k * 8) = *(const u32x4*)(src + k * 8);
        }
        {   // stage V tile: contiguous 16384 floats -> Vs[key][ch], stride 260
            const float* src = Vf + (size_t)kt * 16384 + t * 64;
            float* dst = Vs + (t >> 2) * 260 + (t & 3) * 64;
#pragma unroll
            for (int k = 0; k < 16; ++k)
                *(f4v*)(dst + k * 4) = *(const f4v*)(src + k * 4);
        }
        __syncthreads();

        // S = Q K^T  (wave: 16 q-rows x 64 keys), MFMA
        f4v accs[4] = {zero4, zero4, zero4, zero4};
#pragma unroll
        for (int kc = 0; kc < 8; ++kc) {
#pragma unroll
            for (int ct = 0; ct < 4; ++ct) {
                bf16x8 kf = *(const bf16x8*)(Ks + (ct * 16 + l15) * 264 + kc * 32 + quad * 8);
                accs[ct] = __builtin_amdgcn_mfma_f32_16x16x32_bf16(qf[kc], kf, accs[ct], 0, 0, 0);
            }
        }
        // P = exp(S/256); row-sums; P -> LDS f32, plain (q,key) layout
#pragma unroll
        for (int r = 0; r < 4; ++r) {
            float rs = 0.f;
#pragma unroll
            for (int ct = 0; ct < 4; ++ct) {
                float pe = __expf(accs[ct][r] * (1.0f / 256.0f));
                Psf[(w * 16 + quad * 4 + r) * 65 + ct * 16 + l15] = pe;
                rs += pe;
            }
            rs += __shfl_xor(rs, 1, 64);
            rs += __shfl_xor(rs, 2, 64);
            rs += __shfl_xor(rs, 4, 64);
            rs += __shfl_xor(rs, 8, 64);
            l_acc[r] += rs;
        }
        __syncthreads();

        // O += P @ V, plain VALU: thread owns (q-row vq, channels vg*64..+63)
        for (int key = 0; key < 64; ++key) {
            float pbc = Psf[vq * 65 + key];
            const float* vrow = Vs + key * 260 + vg * 64;
#pragma unroll
            for (int c = 0; c < 64; ++c)
                oacc[c] = fmaf(pbc, vrow[c], oacc[c]);
        }
    }

    // publish row sums, normalize, direct fp32 store (channel-major)
    if (l15 == 0) {
#pragma unroll
        for (int r = 0; r < 4; ++r)
            Ls[w * 16 + quad * 4 + r] = l_acc[r];
    }
    __syncthreads();
    float linv = 1.0f / Ls[vq];
#pragma unroll
    for (int c = 0; c < 64; ++c) {
        int ch = vg * 64 + c;
        Op[(size_t)ch * NTOK + qt * 64 + vq] = oacc[c] * linv;
    }
}

// ---------------------------------------------------------------------------
extern "C" void kernel_launch(void* const* d_in, const int* in_sizes, int n_in,
                              void* d_out, int out_size, void* d_ws, size_t ws_size,
                              hipStream_t stream) {
    (void)in_sizes; (void)n_in; (void)out_size; (void)ws_size;
    const float* feaL  = (const float*)d_in[0];
    const float* feaR  = (const float*)d_in[1];
    const float* Wq    = (const float*)d_in[2];
    const float* bq    = (const float*)d_in[3];
    const float* gq    = (const float*)d_in[4];
    const float* betaq = (const float*)d_in[5];
    const float* mq    = (const float*)d_in[6];
    const float* vq    = (const float*)d_in[7];
    const float* Wk    = (const float*)d_in[8];
    const float* bk    = (const float*)d_in[9];
    const float* gk    = (const float*)d_in[10];
    const float* betak = (const float*)d_in[11];
    const float* mk    = (const float*)d_in[12];
    const float* vk    = (const float*)d_in[13];

    // workspace (bf16): XT 16*MATSZ (18.9MB) | Y 32*MATSZ (37.7MB)
    unsigned short* XT = (unsigned short*)d_ws;
    unsigned short* Yb = XT + (size_t)16 * MATSZ;
    float* out = (float*)d_out;   // fp32: reference output dtype

    dim3 blk(256);
    // XT[s][b][pos][c] = fea[b][c][pos]
    tpose_k<<<dim3(144, 16), blk, 0, stream>>>(feaL, feaR, XT, 256, 2304);
    proj_k<<<dim3(144, 32), blk, 0, stream>>>(XT, Wq, Wk, bq, bk, gq, gk,
                                              betaq, betak, mq, mk, vq, vk, Yb);
    attn_k<<<dim3(36, 16), blk, 0, stream>>>(Yb, feaL, feaR, out);
}

// Round 6
// 502.429 us; speedup vs baseline: 8.4455x; 8.4455x over previous
//
#include <hip/hip_runtime.h>

#define CH    256
#define NTOK  2304
#define MATSZ (CH * NTOK)   // 589824 elements per (b, matrix)

typedef __bf16 bf16x8 __attribute__((ext_vector_type(8)));
typedef float  f4v    __attribute__((ext_vector_type(4)));
typedef unsigned int u32x4 __attribute__((ext_vector_type(4)));

__device__ __forceinline__ unsigned short f2bf(float f) {
    union { float f; unsigned int i; } c;
    c.f = f;
    unsigned int x = c.i;
    x += 0x7fffu + ((x >> 16) & 1u);   // round-to-nearest-even
    return (unsigned short)(x >> 16);
}

__device__ __forceinline__ bf16x8 cvt8(const float* p) {
    union { bf16x8 v; unsigned short s[8]; } u;
#pragma unroll
    for (int i = 0; i < 8; ++i) u.s[i] = f2bf(p[i]);
    return u.v;
}

// ---------------------------------------------------------------------------
// 64x64-tiled transpose + fp32->bf16: in (R x Ccols) row-major fp32 ->
// out (Ccols x R) bf16. blockIdx.y = s*8 + b (s: 0=left 1=right).
// ---------------------------------------------------------------------------
__global__ __launch_bounds__(256) void tpose_k(
    const float* __restrict__ inL,
    const float* __restrict__ inR,
    unsigned short* __restrict__ out, int R, int Ccols)
{
    __shared__ unsigned short tile[64][72];
    int mat = blockIdx.y;
    const float* in = (mat >= 8 ? inR : inL) + (size_t)(mat & 7) * MATSZ;
    unsigned short* o = out + (size_t)mat * MATSZ;
    int tC = Ccols >> 6;
    int r0 = (blockIdx.x / tC) << 6;
    int c0 = (blockIdx.x % tC) << 6;
    int t = threadIdx.x;
    int col = t & 63, rs = t >> 6;
#pragma unroll
    for (int i = 0; i < 16; ++i) {
        int row = rs + i * 4;
        tile[row][col] = f2bf(in[(size_t)(r0 + row) * Ccols + c0 + col]);
    }
    __syncthreads();
#pragma unroll
    for (int i = 0; i < 16; ++i) {
        int crow = rs + i * 4;
        o[(size_t)(c0 + crow) * R + r0 + col] = tile[col][crow];
    }
}

// ---------------------------------------------------------------------------
// Projection: Y[o][pos] = BN(conv1x1(X)), bf16, (o, pos) layout.
// blockIdx.y = p*8 + b; p: 0=q(left) 1=q(right) 2=k(left) 3=k(right).
// (HW-verified correct in R5.)
// ---------------------------------------------------------------------------
__global__ __launch_bounds__(256, 2) void proj_k(
    const unsigned short* __restrict__ XT,   // [2][8][2304][256] bf16
    const float* __restrict__ Wq_, const float* __restrict__ Wk_,
    const float* __restrict__ bq_, const float* __restrict__ bk_,
    const float* __restrict__ gq_, const float* __restrict__ gk_,
    const float* __restrict__ beq_, const float* __restrict__ bek_,
    const float* __restrict__ mq_, const float* __restrict__ mk_,
    const float* __restrict__ vq_, const float* __restrict__ vk_,
    unsigned short* __restrict__ Yout)       // [4][8][MATSZ] bf16
{
    __shared__ __align__(16) unsigned short Xs[64][264];
    int pb = blockIdx.y;
    int p = pb >> 3, b = pb & 7;
    int s = p & 1, br = p >> 1;
    const unsigned short* X = XT + (size_t)(s * 8 + b) * MATSZ;
    const float* W  = br ? Wk_ : Wq_;
    const float* bb = br ? bk_ : bq_;
    const float* gg = br ? gk_ : gq_;
    const float* be = br ? bek_ : beq_;
    const float* mm = br ? mk_ : mq_;
    const float* vv = br ? vk_ : vq_;
    unsigned short* Yo = Yout + (size_t)pb * MATSZ;

    int ot = blockIdx.x & 3, pt = blockIdx.x >> 2;
    int o0 = ot * 64, pos0 = pt * 64;
    int t = threadIdx.x;
    int w = t >> 6, lane = t & 63;
    int l15 = lane & 15, quad = lane >> 4;

    {   // stage XT tile: 64 pos-rows x 256 c
        int r = t >> 2, cq = (t & 3) << 6;
        const unsigned short* src = X + (size_t)(pos0 + r) * CH + cq;
        unsigned short* dst = &Xs[r][cq];
#pragma unroll
        for (int k = 0; k < 8; ++k)
            *(u32x4*)(dst + k * 8) = *(const u32x4*)(src + k * 8);
    }
    bf16x8 wf[8];
    {
        const float* wp = W + (size_t)(o0 + w * 16 + l15) * CH + quad * 8;
#pragma unroll
        for (int kc = 0; kc < 8; ++kc)
            wf[kc] = cvt8(wp + kc * 32);
    }
    __syncthreads();

    f4v zero4 = {0.f, 0.f, 0.f, 0.f};
    f4v acc[4] = {zero4, zero4, zero4, zero4};
#pragma unroll
    for (int kc = 0; kc < 8; ++kc) {
#pragma unroll
        for (int ct = 0; ct < 4; ++ct) {
            bf16x8 xb = *(const bf16x8*)(&Xs[ct * 16 + l15][kc * 32 + quad * 8]);
            acc[ct] = __builtin_amdgcn_mfma_f32_16x16x32_bf16(wf[kc], xb, acc[ct], 0, 0, 0);
        }
    }
#pragma unroll
    for (int r = 0; r < 4; ++r) {
        int o = o0 + w * 16 + quad * 4 + r;
        float scale = gg[o] * rsqrtf(vv[o] + 1e-5f);
        float shift = (bb[o] - mm[o]) * scale + be[o];
#pragma unroll
        for (int ct = 0; ct < 4; ++ct) {
            float val = acc[ct][r] * scale + shift;
            Yo[(size_t)o * NTOK + pos0 + ct * 16 + l15] = f2bf(val);
        }
    }
}

// ---------------------------------------------------------------------------
// Fused attention, full-MFMA: QK^T and PV on matrix cores. Block = 64 Q-rows
// (4 waves x 16), K-loop over 36 x 64-key tiles. Logits S/256 bounded -> no
// max-subtraction; accumulate unnormalized O + row-sums, divide at the end.
// P bridges C-layout -> A-layout via barrier-fenced LDS. FP32 output.
// ---------------------------------------------------------------------------
__global__ __launch_bounds__(256, 2) void attn_k(
    const unsigned short* __restrict__ Y,    // [4][8][MATSZ] projections bf16
    const unsigned short* __restrict__ VT,   // [2][8][256][2304] bf16
    float* __restrict__ out)                 // [2][8][MATSZ] fp32
{
    // Ks 64x264 (33792B) | Vs 256x72 (36864B) | Ps 4x16x72 (9216B) = 79872B
    __shared__ __align__(16) unsigned short lds[64 * 264 + 256 * 72 + 4 * 16 * 72];
    unsigned short* Ks = lds;
    unsigned short* Vs = lds + 64 * 264;
    unsigned short* Ps = lds + 64 * 264 + 256 * 72;

    int ab = blockIdx.y;
    int a = ab >> 3, b = ab & 7;
    int qt = blockIdx.x;
    const unsigned short* Qp = Y + (size_t)(a * 8 + b) * MATSZ;        // q(l)/q(r)
    const unsigned short* Kp = Y + (size_t)((3 - a) * 8 + b) * MATSZ;  // k(r)/k(l)
    const unsigned short* Vp = VT + (size_t)((1 - a) * 8 + b) * MATSZ;
    float* Op = out + (size_t)ab * MATSZ;

    int t = threadIdx.x;
    int w = t >> 6, lane = t & 63;
    int l15 = lane & 15, quad = lane >> 4;

    bf16x8 qf[8];
    {
        const unsigned short* qp = Qp + (size_t)(qt * 64 + w * 16 + l15) * CH + quad * 8;
#pragma unroll
        for (int kc = 0; kc < 8; ++kc) qf[kc] = *(const bf16x8*)(qp + kc * 32);
    }
    f4v zero4 = {0.f, 0.f, 0.f, 0.f};
    f4v acc_o[16];
#pragma unroll
    for (int i = 0; i < 16; ++i) acc_o[i] = zero4;
    float l_acc[4] = {0.f, 0.f, 0.f, 0.f};
    __bf16* Pw = (__bf16*)(Ps + w * 16 * 72);

    for (int kt = 0; kt < 36; ++kt) {
        __syncthreads();
        {   // stage K tile: 64 key-rows x 256 c, stride 264
            int r = t >> 2, cq = (t & 3) << 6;
            const unsigned short* src = Kp + (size_t)(kt * 64 + r) * CH + cq;
            unsigned short* dst = Ks + r * 264 + cq;
#pragma unroll
            for (int k = 0; k < 8; ++k)
                *(u32x4*)(dst + k * 8) = *(const u32x4*)(src + k * 8);
        }
        {   // stage V tile: 256 chan-rows x 64 keys, stride 72
            int c = ((t & 3) << 6) + (t >> 2);
            const unsigned short* src = Vp + (size_t)c * NTOK + kt * 64;
            unsigned short* dst = Vs + c * 72;
#pragma unroll
            for (int k = 0; k < 8; ++k)
                *(u32x4*)(dst + k * 8) = *(const u32x4*)(src + k * 8);
        }
        __syncthreads();

        // S = Q K^T  (wave: 16 q-rows x 64 keys)
        f4v accs[4] = {zero4, zero4, zero4, zero4};
#pragma unroll
        for (int kc = 0; kc < 8; ++kc) {
#pragma unroll
            for (int ct = 0; ct < 4; ++ct) {
                bf16x8 kf = *(const bf16x8*)(Ks + (ct * 16 + l15) * 264 + kc * 32 + quad * 8);
                accs[ct] = __builtin_amdgcn_mfma_f32_16x16x32_bf16(qf[kc], kf, accs[ct], 0, 0, 0);
            }
        }
        // P = exp(S/256); row-sums (row quad*4+r spans the 16 lanes of quad)
        float pv[4][4];
#pragma unroll
        for (int r = 0; r < 4; ++r) {
            float rs = 0.f;
#pragma unroll
            for (int ct = 0; ct < 4; ++ct) {
                float pe = __expf(accs[ct][r] * (1.0f / 256.0f));
                pv[ct][r] = pe;
                rs += pe;
            }
            rs += __shfl_xor(rs, 1, 64);
            rs += __shfl_xor(rs, 2, 64);
            rs += __shfl_xor(rs, 4, 64);
            rs += __shfl_xor(rs, 8, 64);
            l_acc[r] += rs;
        }
        // P: C-layout -> LDS (per-wave region), barrier-fenced round trip
#pragma unroll
        for (int r = 0; r < 4; ++r)
#pragma unroll
            for (int ct = 0; ct < 4; ++ct)
                Pw[(quad * 4 + r) * 72 + ct * 16 + l15] = (__bf16)pv[ct][r];
        __syncthreads();
        // O += P @ V  (P read back in A-operand layout)
#pragma unroll
        for (int kc = 0; kc < 2; ++kc) {
            bf16x8 pf = *(const bf16x8*)(Pw + l15 * 72 + kc * 32 + quad * 8);
#pragma unroll
            for (int ct = 0; ct < 16; ++ct) {
                bf16x8 vf = *(const bf16x8*)(Vs + (ct * 16 + l15) * 72 + kc * 32 + quad * 8);
                acc_o[ct] = __builtin_amdgcn_mfma_f32_16x16x32_bf16(pf, vf, acc_o[ct], 0, 0, 0);
            }
        }
    }

    // epilogue: normalize, fp32 transpose through LDS, coalesced stores
    __syncthreads();
    float* Ot = (float*)lds;   // [256][73] fp32 = 74752B, fits in 79872B
#pragma unroll
    for (int ct = 0; ct < 16; ++ct)
#pragma unroll
        for (int r = 0; r < 4; ++r) {
            float val = acc_o[ct][r] / l_acc[r];
            Ot[(ct * 16 + l15) * 73 + (w * 16 + quad * 4 + r)] = val;
        }
    __syncthreads();
    for (int cg = 0; cg < 64; ++cg) {
        int c = cg * 4 + w;
        Op[(size_t)c * NTOK + qt * 64 + lane] = Ot[c * 73 + lane];
    }
}

// ---------------------------------------------------------------------------
extern "C" void kernel_launch(void* const* d_in, const int* in_sizes, int n_in,
                              void* d_out, int out_size, void* d_ws, size_t ws_size,
                              hipStream_t stream) {
    (void)in_sizes; (void)n_in; (void)out_size; (void)ws_size;
    const float* feaL  = (const float*)d_in[0];
    const float* feaR  = (const float*)d_in[1];
    const float* Wq    = (const float*)d_in[2];
    const float* bq    = (const float*)d_in[3];
    const float* gq    = (const float*)d_in[4];
    const float* betaq = (const float*)d_in[5];
    const float* mq    = (const float*)d_in[6];
    const float* vq    = (const float*)d_in[7];
    const float* Wk    = (const float*)d_in[8];
    const float* bk    = (const float*)d_in[9];
    const float* gk    = (const float*)d_in[10];
    const float* betak = (const float*)d_in[11];
    const float* mk    = (const float*)d_in[12];
    const float* vk    = (const float*)d_in[13];

    // workspace (bf16): XT/VT alias 16*MATSZ (18.9MB) | Y 32*MATSZ (37.7MB)
    unsigned short* XT = (unsigned short*)d_ws;   // reused as VT after proj
    unsigned short* VT = XT;
    unsigned short* Yb = XT + (size_t)16 * MATSZ;
    float* out = (float*)d_out;   // fp32: reference output dtype

    dim3 blk(256);
    // XT[s][b][pos][c] = fea[b][c][pos]
    tpose_k<<<dim3(144, 16), blk, 0, stream>>>(feaL, feaR, XT, 256, 2304);
    proj_k<<<dim3(144, 32), blk, 0, stream>>>(XT, Wq, Wk, bq, bk, gq, gk,
                                              betaq, betak, mq, mk, vq, vk, Yb);
    // VT[s][b][c][n] = fea_flat[n*256+c]
    tpose_k<<<dim3(144, 16), blk, 0, stream>>>(feaL, feaR, VT, 2304, 256);
    attn_k<<<dim3(36, 16), blk, 0, stream>>>(Yb, VT, out);
}

// Round 7
// 489.082 us; speedup vs baseline: 8.6760x; 1.0273x over previous
//
#include <hip/hip_runtime.h>

#define CH    256
#define NTOK  2304
#define MATSZ (CH * NTOK)   // 589824 elements per (b, matrix)

typedef __bf16 bf16x8 __attribute__((ext_vector_type(8)));
typedef float  f4v    __attribute__((ext_vector_type(4)));
typedef unsigned int u32x4 __attribute__((ext_vector_type(4)));

__device__ __forceinline__ unsigned short f2bf(float f) {
    union { float f; unsigned int i; } c;
    c.f = f;
    unsigned int x = c.i;
    x += 0x7fffu + ((x >> 16) & 1u);   // round-to-nearest-even
    return (unsigned short)(x >> 16);
}

__device__ __forceinline__ bf16x8 cvt8(const float* p) {
    union { bf16x8 v; unsigned short s[8]; } u;
#pragma unroll
    for (int i = 0; i < 8; ++i) u.s[i] = f2bf(p[i]);
    return u.v;
}

// ---------------------------------------------------------------------------
// 64x64-tiled transpose + fp32->bf16: in (R x Ccols) row-major fp32 ->
// out (Ccols x R) bf16. blockIdx.y = s*8 + b (s: 0=left 1=right).
// ---------------------------------------------------------------------------
__global__ __launch_bounds__(256) void tpose_k(
    const float* __restrict__ inL,
    const float* __restrict__ inR,
    unsigned short* __restrict__ out, int R, int Ccols)
{
    __shared__ unsigned short tile[64][72];
    int mat = blockIdx.y;
    const float* in = (mat >= 8 ? inR : inL) + (size_t)(mat & 7) * MATSZ;
    unsigned short* o = out + (size_t)mat * MATSZ;
    int tC = Ccols >> 6;
    int r0 = (blockIdx.x / tC) << 6;
    int c0 = (blockIdx.x % tC) << 6;
    int t = threadIdx.x;
    int col = t & 63, rs = t >> 6;
#pragma unroll
    for (int i = 0; i < 16; ++i) {
        int row = rs + i * 4;
        tile[row][col] = f2bf(in[(size_t)(r0 + row) * Ccols + c0 + col]);
    }
    __syncthreads();
#pragma unroll
    for (int i = 0; i < 16; ++i) {
        int crow = rs + i * 4;
        o[(size_t)(c0 + crow) * R + r0 + col] = tile[col][crow];
    }
}

// ---------------------------------------------------------------------------
// Projection: Y[o][pos] = BN(conv1x1(X)), bf16, (o, pos) layout.
// blockIdx.y = p*8 + b; p: 0=q(left) 1=q(right) 2=k(left) 3=k(right).
// (HW-verified correct in R5/R6.)
// ---------------------------------------------------------------------------
__global__ __launch_bounds__(256, 2) void proj_k(
    const unsigned short* __restrict__ XT,   // [2][8][2304][256] bf16
    const float* __restrict__ Wq_, const float* __restrict__ Wk_,
    const float* __restrict__ bq_, const float* __restrict__ bk_,
    const float* __restrict__ gq_, const float* __restrict__ gk_,
    const float* __restrict__ beq_, const float* __restrict__ bek_,
    const float* __restrict__ mq_, const float* __restrict__ mk_,
    const float* __restrict__ vq_, const float* __restrict__ vk_,
    unsigned short* __restrict__ Yout)       // [4][8][MATSZ] bf16
{
    __shared__ __align__(16) unsigned short Xs[64][264];
    int pb = blockIdx.y;
    int p = pb >> 3, b = pb & 7;
    int s = p & 1, br = p >> 1;
    const unsigned short* X = XT + (size_t)(s * 8 + b) * MATSZ;
    const float* W  = br ? Wk_ : Wq_;
    const float* bb = br ? bk_ : bq_;
    const float* gg = br ? gk_ : gq_;
    const float* be = br ? bek_ : beq_;
    const float* mm = br ? mk_ : mq_;
    const float* vv = br ? vk_ : vq_;
    unsigned short* Yo = Yout + (size_t)pb * MATSZ;

    int ot = blockIdx.x & 3, pt = blockIdx.x >> 2;
    int o0 = ot * 64, pos0 = pt * 64;
    int t = threadIdx.x;
    int w = t >> 6, lane = t & 63;
    int l15 = lane & 15, quad = lane >> 4;

    {   // stage XT tile: 64 pos-rows x 256 c
        int r = t >> 2, cq = (t & 3) << 6;
        const unsigned short* src = X + (size_t)(pos0 + r) * CH + cq;
        unsigned short* dst = &Xs[r][cq];
#pragma unroll
        for (int k = 0; k < 8; ++k)
            *(u32x4*)(dst + k * 8) = *(const u32x4*)(src + k * 8);
    }
    bf16x8 wf[8];
    {
        const float* wp = W + (size_t)(o0 + w * 16 + l15) * CH + quad * 8;
#pragma unroll
        for (int kc = 0; kc < 8; ++kc)
            wf[kc] = cvt8(wp + kc * 32);
    }
    __syncthreads();

    f4v zero4 = {0.f, 0.f, 0.f, 0.f};
    f4v acc[4] = {zero4, zero4, zero4, zero4};
#pragma unroll
    for (int kc = 0; kc < 8; ++kc) {
#pragma unroll
        for (int ct = 0; ct < 4; ++ct) {
            bf16x8 xb = *(const bf16x8*)(&Xs[ct * 16 + l15][kc * 32 + quad * 8]);
            acc[ct] = __builtin_amdgcn_mfma_f32_16x16x32_bf16(wf[kc], xb, acc[ct], 0, 0, 0);
        }
    }
#pragma unroll
    for (int r = 0; r < 4; ++r) {
        int o = o0 + w * 16 + quad * 4 + r;
        float scale = gg[o] * rsqrtf(vv[o] + 1e-5f);
        float shift = (bb[o] - mm[o]) * scale + be[o];
#pragma unroll
        for (int ct = 0; ct < 4; ++ct) {
            float val = acc[ct][r] * scale + shift;
            Yo[(size_t)o * NTOK + pos0 + ct * 16 + l15] = f2bf(val);
        }
    }
}

// ---------------------------------------------------------------------------
// Fused attention, full-MFMA + register-prefetch pipeline.
// Block = 64 Q-rows (4 waves x 16), K-loop over 36 x 64-key tiles.
// Pipeline: [barrier; ds_write staged regs; barrier; issue kt+1 global loads
// into regs; compute kt] -- compute hides the HBM latency, vmcnt wait lands
// before next iteration's ds_write. P-bridge is per-wave private LDS: only a
// wave-local s_waitcnt lgkmcnt(0) is needed (no block barrier). FP32 output.
// ---------------------------------------------------------------------------
__global__ __launch_bounds__(256, 2) void attn_k(
    const unsigned short* __restrict__ Y,    // [4][8][MATSZ] projections bf16
    const unsigned short* __restrict__ VT,   // [2][8][256][2304] bf16
    float* __restrict__ out)                 // [2][8][MATSZ] fp32
{
    // Ks 64x264 (33792B) | Vs 256x72 (36864B) | Ps 4x16x72 (9216B) = 79872B
    __shared__ __align__(16) unsigned short lds[64 * 264 + 256 * 72 + 4 * 16 * 72];
    unsigned short* Ks = lds;
    unsigned short* Vs = lds + 64 * 264;
    unsigned short* Ps = lds + 64 * 264 + 256 * 72;

    int ab = blockIdx.y;
    int a = ab >> 3, b = ab & 7;
    int qt = blockIdx.x;
    const unsigned short* Qp = Y + (size_t)(a * 8 + b) * MATSZ;        // q(l)/q(r)
    const unsigned short* Kp = Y + (size_t)((3 - a) * 8 + b) * MATSZ;  // k(r)/k(l)
    const unsigned short* Vp = VT + (size_t)((1 - a) * 8 + b) * MATSZ;
    float* Op = out + (size_t)ab * MATSZ;

    int t = threadIdx.x;
    int w = t >> 6, lane = t & 63;
    int l15 = lane & 15, quad = lane >> 4;

    // staging coordinates (verified in R6)
    int kr = t >> 2, kc0 = (t & 3) << 6;               // K: row, col-quarter
    int vc = ((t & 3) << 6) + (t >> 2);                // V: channel row
    const unsigned short* ksrc0 = Kp + (size_t)kr * CH + kc0;
    const unsigned short* vsrc0 = Vp + (size_t)vc * NTOK;
    unsigned short* kdst = Ks + kr * 264 + kc0;
    unsigned short* vdst = Vs + vc * 72;

    bf16x8 qf[8];
    {
        const unsigned short* qp = Qp + (size_t)(qt * 64 + w * 16 + l15) * CH + quad * 8;
#pragma unroll
        for (int kc = 0; kc < 8; ++kc) qf[kc] = *(const bf16x8*)(qp + kc * 32);
    }
    f4v zero4 = {0.f, 0.f, 0.f, 0.f};
    f4v acc_o[16];
#pragma unroll
    for (int i = 0; i < 16; ++i) acc_o[i] = zero4;
    float l_acc[4] = {0.f, 0.f, 0.f, 0.f};
    __bf16* Pw = (__bf16*)(Ps + w * 16 * 72);

    // preload tile kt=0 into registers
    u32x4 kreg[8], vreg[8];
#pragma unroll
    for (int k = 0; k < 8; ++k) kreg[k] = *(const u32x4*)(ksrc0 + k * 8);
#pragma unroll
    for (int k = 0; k < 8; ++k) vreg[k] = *(const u32x4*)(vsrc0 + k * 8);

    for (int kt = 0; kt < 36; ++kt) {
        __syncthreads();     // previous iteration's LDS readers done
#pragma unroll
        for (int k = 0; k < 8; ++k) *(u32x4*)(kdst + k * 8) = kreg[k];
#pragma unroll
        for (int k = 0; k < 8; ++k) *(u32x4*)(vdst + k * 8) = vreg[k];
        __syncthreads();     // staged tile visible

        if (kt < 35) {       // prefetch kt+1; compute below hides the latency
            const unsigned short* kn = ksrc0 + (size_t)(kt + 1) * 64 * CH;
            const unsigned short* vn = vsrc0 + (size_t)(kt + 1) * 64;
#pragma unroll
            for (int k = 0; k < 8; ++k) kreg[k] = *(const u32x4*)(kn + k * 8);
#pragma unroll
            for (int k = 0; k < 8; ++k) vreg[k] = *(const u32x4*)(vn + k * 8);
        }

        // S = Q K^T  (wave: 16 q-rows x 64 keys)
        f4v accs[4] = {zero4, zero4, zero4, zero4};
#pragma unroll
        for (int kc = 0; kc < 8; ++kc) {
#pragma unroll
            for (int ct = 0; ct < 4; ++ct) {
                bf16x8 kf = *(const bf16x8*)(Ks + (ct * 16 + l15) * 264 + kc * 32 + quad * 8);
                accs[ct] = __builtin_amdgcn_mfma_f32_16x16x32_bf16(qf[kc], kf, accs[ct], 0, 0, 0);
            }
        }
        // P = exp(S/256); row-sums (row quad*4+r spans the 16 lanes of quad)
        float pv[4][4];
#pragma unroll
        for (int r = 0; r < 4; ++r) {
            float rs = 0.f;
#pragma unroll
            for (int ct = 0; ct < 4; ++ct) {
                float pe = __expf(accs[ct][r] * (1.0f / 256.0f));
                pv[ct][r] = pe;
                rs += pe;
            }
            rs += __shfl_xor(rs, 1, 64);
            rs += __shfl_xor(rs, 2, 64);
            rs += __shfl_xor(rs, 4, 64);
            rs += __shfl_xor(rs, 8, 64);
            l_acc[r] += rs;
        }
        // P: C-layout -> per-wave LDS region -> A-layout (wave-local fence)
#pragma unroll
        for (int r = 0; r < 4; ++r)
#pragma unroll
            for (int ct = 0; ct < 4; ++ct)
                Pw[(quad * 4 + r) * 72 + ct * 16 + l15] = (__bf16)pv[ct][r];
        __asm__ volatile("s_waitcnt lgkmcnt(0)" ::: "memory");
        // O += P @ V  (P read back in A-operand layout)
#pragma unroll
        for (int kc = 0; kc < 2; ++kc) {
            bf16x8 pf = *(const bf16x8*)(Pw + l15 * 72 + kc * 32 + quad * 8);
#pragma unroll
            for (int ct = 0; ct < 16; ++ct) {
                bf16x8 vf = *(const bf16x8*)(Vs + (ct * 16 + l15) * 72 + kc * 32 + quad * 8);
                acc_o[ct] = __builtin_amdgcn_mfma_f32_16x16x32_bf16(pf, vf, acc_o[ct], 0, 0, 0);
            }
        }
    }

    // epilogue: normalize, fp32 transpose through LDS, coalesced stores
    __syncthreads();
    float* Ot = (float*)lds;   // [256][73] fp32 = 74752B, fits in 79872B
#pragma unroll
    for (int ct = 0; ct < 16; ++ct)
#pragma unroll
        for (int r = 0; r < 4; ++r) {
            float val = acc_o[ct][r] / l_acc[r];
            Ot[(ct * 16 + l15) * 73 + (w * 16 + quad * 4 + r)] = val;
        }
    __syncthreads();
    for (int cg = 0; cg < 64; ++cg) {
        int c = cg * 4 + w;
        Op[(size_t)c * NTOK + qt * 64 + lane] = Ot[c * 73 + lane];
    }
}

// ---------------------------------------------------------------------------
extern "C" void kernel_launch(void* const* d_in, const int* in_sizes, int n_in,
                              void* d_out, int out_size, void* d_ws, size_t ws_size,
                              hipStream_t stream) {
    (void)in_sizes; (void)n_in; (void)out_size; (void)ws_size;
    const float* feaL  = (const float*)d_in[0];
    const float* feaR  = (const float*)d_in[1];
    const float* Wq    = (const float*)d_in[2];
    const float* bq    = (const float*)d_in[3];
    const float* gq    = (const float*)d_in[4];
    const float* betaq = (const float*)d_in[5];
    const float* mq    = (const float*)d_in[6];
    const float* vq    = (const float*)d_in[7];
    const float* Wk    = (const float*)d_in[8];
    const float* bk    = (const float*)d_in[9];
    const float* gk    = (const float*)d_in[10];
    const float* betak = (const float*)d_in[11];
    const float* mk    = (const float*)d_in[12];
    const float* vk    = (const float*)d_in[13];

    // workspace (bf16): XT/VT alias 16*MATSZ (18.9MB) | Y 32*MATSZ (37.7MB)
    unsigned short* XT = (unsigned short*)d_ws;   // reused as VT after proj
    unsigned short* VT = XT;
    unsigned short* Yb = XT + (size_t)16 * MATSZ;
    float* out = (float*)d_out;   // fp32: reference output dtype

    dim3 blk(256);
    // XT[s][b][pos][c] = fea[b][c][pos]
    tpose_k<<<dim3(144, 16), blk, 0, stream>>>(feaL, feaR, XT, 256, 2304);
    proj_k<<<dim3(144, 32), blk, 0, stream>>>(XT, Wq, Wk, bq, bk, gq, gk,
                                              betaq, betak, mq, mk, vq, vk, Yb);
    // VT[s][b][c][n] = fea_flat[n*256+c]
    tpose_k<<<dim3(144, 16), blk, 0, stream>>>(feaL, feaR, VT, 2304, 256);
    attn_k<<<dim3(36, 16), blk, 0, stream>>>(Yb, VT, out);
}